// Round 7
// baseline (55.839 us; speedup 1.0000x reference)
//
#include <hip/hip_runtime.h>
#include <hip/hip_bf16.h>
#include <stdint.h>

typedef __bf16 bf16_t;
typedef __bf16 bf16x8 __attribute__((ext_vector_type(8)));
typedef float f32x4 __attribute__((ext_vector_type(4)));

#define L2E 1.44269504088896340736f

static __device__ __forceinline__ f32x4 mfma16(bf16x8 a, bf16x8 b, f32x4 c) {
  return __builtin_amdgcn_mfma_f32_16x16x32_bf16(a, b, c, 0, 0, 0);
}

static __device__ __forceinline__ void gload_lds16(const void* g, void* l) {
  __builtin_amdgcn_global_load_lds(
      (const __attribute__((address_space(1))) uint32_t*)g,
      (__attribute__((address_space(3))) uint32_t*)l, 16, 0, 0);
}

// ---------------- kernel 0: weights -> bf16, transposed to [proj][n=64][k=1024] ----
// proj 0 (Q) folds the 1/sqrt(64) scale.
__global__ __launch_bounds__(256) void wt_kernel(const float* __restrict__ Wq,
                                                 const float* __restrict__ Wk,
                                                 const float* __restrict__ Wv,
                                                 bf16_t* __restrict__ Wt) {
  int gid = blockIdx.x * 256 + threadIdx.x;  // 0 .. 196607
  int proj = gid >> 16;
  int rem = gid & 65535;          // = k*64 + n (row-major read, coalesced)
  int k = rem >> 6, n = rem & 63;
  const float* W = (proj == 0) ? Wq : (proj == 1) ? Wk : Wv;
  float v = W[rem];
  if (proj == 0) v *= 0.125f;
  Wt[proj * 65536 + n * 1024 + k] = (bf16_t)v;
}

// ---------------- kernel 1: QKV projection, full-K per wave, W in LDS dbuf ---------
// grid 768 (3 blocks/CU exactly), block 128 (2 waves), 32 rows/block, full K=1024.
// K in 8 chunks of 128: stage W(c+1) (gload_lds, swizzled source) + issue X(c+1)
// (8 float4/lane straight to regs) -> 1 barrier -> compute chunk c. No K-merge.
__global__ __launch_bounds__(128) void proj_kernel(
    const float* __restrict__ Xq, const float* __restrict__ Xk, const float* __restrict__ Xv,
    const bf16_t* __restrict__ Wt,
    bf16_t* __restrict__ Qb, bf16_t* __restrict__ Kb, bf16_t* __restrict__ Vt) {
  __shared__ alignas(16) char Wl[2][16384];   // dbuf W chunk [64 n][128 k] bf16, swz
  __shared__ bf16_t Vb[2][16][68];            // per-wave V transpose staging

  int tid = threadIdx.x;
  int w = tid >> 6, lane = tid & 63;
  int l15 = lane & 15, g = lane >> 4;
  int bid = blockIdx.x;
  int p = bid >> 8, rt = bid & 255;
  int m0 = rt * 32;
  const float* X = (p == 0) ? Xq : (p == 1) ? Xk : Xv;
  const char* wbase = (const char*)(Wt + (size_t)p * 65536);  // rows of 2048 B

  // W staging: instr i covers dest bytes [i*2048 + w*1024, +1024) (lane*16 implicit)
  int sn = w * 4 + (lane >> 4);       // + i*8 = n
  int skb = (lane & 15) * 16;         // k-byte within 256B row segment

  auto stageW = [&](int c, int buf) {
#pragma unroll
    for (int i = 0; i < 8; ++i) {
      int n = i * 8 + sn;
      const char* src = wbase + (size_t)n * 2048 + c * 256 + (skb ^ ((n & 7) << 4));
      gload_lds16(src, &Wl[buf][i * 2048 + w * 1024]);
    }
  };

  const float* xrow = X + (size_t)(m0 + w * 16 + l15) * 1024 + g * 8;

  auto issueX = [&](int c, float4* xr) {
    const float* b = xrow + c * 128;
#pragma unroll
    for (int j = 0; j < 4; ++j) {
      xr[2 * j] = *(const float4*)(b + j * 32);
      xr[2 * j + 1] = *(const float4*)(b + j * 32 + 4);
    }
  };

  f32x4 acc[4] = {};

  auto compute = [&](int c, const float4* xr) {
    const char* wb = &Wl[c & 1][0];
#pragma unroll
    for (int j = 0; j < 4; ++j) {
      bf16x8 af;
      af[0] = (bf16_t)xr[2 * j].x; af[1] = (bf16_t)xr[2 * j].y;
      af[2] = (bf16_t)xr[2 * j].z; af[3] = (bf16_t)xr[2 * j].w;
      af[4] = (bf16_t)xr[2 * j + 1].x; af[5] = (bf16_t)xr[2 * j + 1].y;
      af[6] = (bf16_t)xr[2 * j + 1].z; af[7] = (bf16_t)xr[2 * j + 1].w;
#pragma unroll
      for (int ct = 0; ct < 4; ++ct) {
        int n = ct * 16 + l15;
        bf16x8 bfr = *(const bf16x8*)(wb + n * 256 + ((j * 64 + g * 16) ^ ((n & 7) << 4)));
        acc[ct] = mfma16(af, bfr, acc[ct]);
      }
    }
  };

  float4 xA[8], xB[8];
  stageW(0, 0);
  issueX(0, xA);
#pragma unroll
  for (int c = 0; c < 8; ++c) {
    __syncthreads();                 // drains W(c) + X(c); WAR-safe via dbuf
    if (c < 7) {
      stageW(c + 1, (c + 1) & 1);
      if (c & 1) issueX(c + 1, xA); else issueX(c + 1, xB);
    }
    if (c & 1) compute(c, xB); else compute(c, xA);
  }

  // ---- epilogue: C row = w*16 + g*4 + r, col = ct*16 + l15 ----
  if (p < 2) {
    bf16_t* Ob = (p == 0) ? Qb : Kb;
    size_t rbase = (size_t)(m0 + w * 16 + g * 4) * 64 + l15;
#pragma unroll
    for (int ct = 0; ct < 4; ++ct)
#pragma unroll
      for (int r = 0; r < 4; ++r)
        Ob[rbase + (size_t)r * 64 + ct * 16] = (bf16_t)acc[ct][r];
  } else {
#pragma unroll
    for (int ct = 0; ct < 4; ++ct)
#pragma unroll
      for (int r = 0; r < 4; ++r)
        Vb[w][g * 4 + r][ct * 16 + l15] = (bf16_t)acc[ct][r];
    // wave-private buffer: compiler inserts the lgkm wait for the re-reads
    int d = lane;
    bf16_t tmp[16];
#pragma unroll
    for (int s = 0; s < 16; ++s) tmp[s] = Vb[w][s][d];
    int b = rt >> 6;
    int s0 = (m0 & 2047) + w * 16;
    bf16_t* dst = Vt + ((size_t)(b * 64 + d)) * 2048 + s0;
    *(uint4*)dst = *(const uint4*)&tmp[0];
    *(uint4*)(dst + 8) = *(const uint4*)&tmp[8];
  }
}

// ---------------- kernel 2: causal flash attention, QBLK=32, KV-split 8 waves ------
// grid (64, 4), block 512 (8 waves), ~1 block/CU. Block owns 32 q-rows (2 row-groups
// per wave); wave w handles KV tiles w, w+8, ... with private flash state; merged at
// the end via LDS. K/V frags straight from L2/L3; no barriers in the main loop.
#define NW 8
__global__ __launch_bounds__(512) void attn_kernel(
    const bf16_t* __restrict__ Qb, const bf16_t* __restrict__ Kb,
    const bf16_t* __restrict__ Vt, float* __restrict__ Out) {
  __shared__ alignas(16) char Psm[NW * 4096];   // per-wave 32x64 P tiles (swizzled)
  __shared__ float accL[NW][32][64];            // 64 KB
  __shared__ float mL[NW][32];
  __shared__ float lL[NW][32];

  int b = blockIdx.y;
  int x = blockIdx.x;
  int qt = (b >= 2) ? (63 - x) : x;    // pair heavy+light across CUs
  int q0 = qt * 32;
  int tid = threadIdx.x;
  int w = tid >> 6, lane = tid & 63;
  int l15 = lane & 15, g = lane >> 4;
  char* Pw = Psm + w * 4096;

  bf16x8 qf[2][2];
#pragma unroll
  for (int h = 0; h < 2; ++h) {
    size_t qrow = (size_t)(b * 2048 + q0 + h * 16 + l15) * 64;
    qf[h][0] = *(const bf16x8*)(Qb + qrow + g * 8);
    qf[h][1] = *(const bf16x8*)(Qb + qrow + 32 + g * 8);
  }

  float m_run[2][4], l_run[2][4];
  f32x4 acc_o[2][4] = {};
#pragma unroll
  for (int h = 0; h < 2; ++h)
#pragma unroll
    for (int r = 0; r < 4; ++r) { m_run[h][r] = -1e30f; l_run[h][r] = 0.f; }

  int ntiles = (q0 + 95) >> 6;         // ceil((q0+32)/64)
  const bf16_t* kbase = Kb + (size_t)b * 2048 * 64;
  const bf16_t* vbase = Vt + (size_t)b * 64 * 2048;

  for (int t = w; t < ntiles; t += NW) {
    int kv0 = t * 64;
    // S = Q K^T  (K frags shared across the two row-groups)
    f32x4 s[2][4] = {};
#pragma unroll
    for (int ct = 0; ct < 4; ++ct) {
      const bf16_t* kr = kbase + (size_t)(kv0 + ct * 16 + l15) * 64 + g * 8;
      bf16x8 kf0 = *(const bf16x8*)kr;
      bf16x8 kf1 = *(const bf16x8*)(kr + 32);
#pragma unroll
      for (int h = 0; h < 2; ++h) {
        s[h][ct] = mfma16(qf[h][0], kf0, s[h][ct]);
        s[h][ct] = mfma16(qf[h][1], kf1, s[h][ct]);
      }
    }
    if (t == ntiles - 1) {  // diagonal tile: causal mask
#pragma unroll
      for (int h = 0; h < 2; ++h)
#pragma unroll
        for (int ct = 0; ct < 4; ++ct)
#pragma unroll
          for (int r = 0; r < 4; ++r) {
            int kg_ = kv0 + ct * 16 + l15;
            int qg_ = q0 + h * 16 + g * 4 + r;
            if (kg_ > qg_) s[h][ct][r] = -1e30f;
          }
    }

    // online softmax (row = h*16 + g*4 + r)
#pragma unroll
    for (int h = 0; h < 2; ++h)
#pragma unroll
      for (int r = 0; r < 4; ++r) {
        float mx = fmaxf(fmaxf(s[h][0][r], s[h][1][r]), fmaxf(s[h][2][r], s[h][3][r]));
        mx = fmaxf(mx, __shfl_xor(mx, 1, 64));
        mx = fmaxf(mx, __shfl_xor(mx, 2, 64));
        mx = fmaxf(mx, __shfl_xor(mx, 4, 64));
        mx = fmaxf(mx, __shfl_xor(mx, 8, 64));
        float mnew = fmaxf(m_run[h][r], mx);
        float scale = exp2f((m_run[h][r] - mnew) * L2E);
        m_run[h][r] = mnew;
        float ps = 0.f;
        int qrl = h * 16 + g * 4 + r;
        char* pb = Pw + qrl * 128;
        int swp = (qrl & 7) << 4;
#pragma unroll
        for (int ct = 0; ct < 4; ++ct) {
          float p = exp2f((s[h][ct][r] - mnew) * L2E);
          ps += p;
          *(bf16_t*)(pb + ((ct * 32 + l15 * 2) ^ swp)) = (bf16_t)p;
        }
        ps += __shfl_xor(ps, 1, 64);
        ps += __shfl_xor(ps, 2, 64);
        ps += __shfl_xor(ps, 4, 64);
        ps += __shfl_xor(ps, 8, 64);
        l_run[h][r] = l_run[h][r] * scale + ps;
#pragma unroll
        for (int dt = 0; dt < 4; ++dt) acc_o[h][dt][r] *= scale;
      }

    // O += P V   (V frags shared across the two row-groups)
    int swpr = (l15 & 7) << 4;
#pragma unroll
    for (int ks = 0; ks < 2; ++ks) {
      bf16x8 pf0 = *(const bf16x8*)(Pw + l15 * 128 + ((ks * 64 + g * 16) ^ swpr));
      bf16x8 pf1 = *(const bf16x8*)(Pw + (16 + l15) * 128 + ((ks * 64 + g * 16) ^ swpr));
#pragma unroll
      for (int dt = 0; dt < 4; ++dt) {
        const bf16_t* vr = vbase + (size_t)(dt * 16 + l15) * 2048 + kv0 + ks * 32 + g * 8;
        bf16x8 vf = *(const bf16x8*)vr;
        acc_o[0][dt] = mfma16(pf0, vf, acc_o[0][dt]);
        acc_o[1][dt] = mfma16(pf1, vf, acc_o[1][dt]);
      }
    }
  }

  // publish per-wave partial state
  if (l15 == 0) {
#pragma unroll
    for (int h = 0; h < 2; ++h)
#pragma unroll
      for (int r = 0; r < 4; ++r) {
        mL[w][h * 16 + g * 4 + r] = m_run[h][r];
        lL[w][h * 16 + g * 4 + r] = l_run[h][r];
      }
  }
#pragma unroll
  for (int h = 0; h < 2; ++h)
#pragma unroll
    for (int dt = 0; dt < 4; ++dt)
#pragma unroll
      for (int r = 0; r < 4; ++r)
        accL[w][h * 16 + g * 4 + r][dt * 16 + l15] = acc_o[h][dt][r];
  __syncthreads();

  // merge 8 partials: thread -> (row = tid>>4, 4 d's = (tid&15)*4)
  int row = tid >> 4, c0 = (tid & 15) * 4;
  float M = -1e30f;
#pragma unroll
  for (int w2 = 0; w2 < NW; ++w2) M = fmaxf(M, mL[w2][row]);
  float L = 0.f;
  f32x4 o = {0.f, 0.f, 0.f, 0.f};
#pragma unroll
  for (int w2 = 0; w2 < NW; ++w2) {
    float sc = exp2f((mL[w2][row] - M) * L2E);
    L += lL[w2][row] * sc;
    f32x4 a = *(const f32x4*)&accL[w2][row][c0];
    o[0] += sc * a[0]; o[1] += sc * a[1]; o[2] += sc * a[2]; o[3] += sc * a[3];
  }
  float inv = 1.0f / L;
  float4 o4 = {o[0] * inv, o[1] * inv, o[2] * inv, o[3] * inv};
  *(float4*)&Out[(size_t)(b * 2048 + q0 + row) * 64 + c0] = o4;
}

extern "C" void kernel_launch(void* const* d_in, const int* in_sizes, int n_in,
                              void* d_out, int out_size, void* d_ws, size_t ws_size,
                              hipStream_t stream) {
  const float* Xk = (const float*)d_in[0];
  const float* Xv = (const float*)d_in[1];
  const float* Xq = (const float*)d_in[2];
  const float* Wq = (const float*)d_in[3];
  const float* Wk = (const float*)d_in[4];
  const float* Wv = (const float*)d_in[5];
  float* Out = (float*)d_out;

  bf16_t* ws = (bf16_t*)d_ws;
  bf16_t* Qb = ws;                 // [8192][64]   bf16, pre-scaled by 0.125
  bf16_t* Kb = ws + 524288;        // [8192][64]   bf16
  bf16_t* Vt = ws + 1048576;       // [4][64][2048] bf16 (V transposed)
  bf16_t* Wt = ws + 1572864;       // [3][64][1024] bf16 (weights transposed)

  wt_kernel<<<dim3(768), dim3(256), 0, stream>>>(Wq, Wk, Wv, Wt);
  proj_kernel<<<dim3(768), dim3(128), 0, stream>>>(Xq, Xk, Xv, Wt, Qb, Kb, Vt);
  attn_kernel<<<dim3(64, 4), dim3(512), 0, stream>>>(Qb, Kb, Vt, Out);
}

// Round 8
// 52.854 us; speedup vs baseline: 1.0565x; 1.0565x over previous
//
#include <hip/hip_runtime.h>
#include <hip/hip_bf16.h>
#include <stdint.h>

typedef __bf16 bf16_t;
typedef __bf16 bf16x8 __attribute__((ext_vector_type(8)));
typedef float f32x4 __attribute__((ext_vector_type(4)));

#define L2E 1.44269504088896340736f

static __device__ __forceinline__ f32x4 mfma16(bf16x8 a, bf16x8 b, f32x4 c) {
  return __builtin_amdgcn_mfma_f32_16x16x32_bf16(a, b, c, 0, 0, 0);
}

static __device__ __forceinline__ void gload_lds16(const void* g, void* l) {
  __builtin_amdgcn_global_load_lds(
      (const __attribute__((address_space(1))) uint32_t*)g,
      (__attribute__((address_space(3))) uint32_t*)l, 16, 0, 0);
}

static __device__ __forceinline__ float bf2f(uint16_t u) {
  union { uint32_t i; float f; } v; v.i = (uint32_t)u << 16; return v.f;
}

// lgkm-only barrier: syncs LDS visibility without draining the vmcnt queue,
// so cross-tile global_load_lds prefetches stay in flight (T4).
static __device__ __forceinline__ void lds_barrier() {
  asm volatile("s_waitcnt lgkmcnt(0)" ::: "memory");
  __builtin_amdgcn_s_barrier();
}

// ---------------- kernel 0: weights -> bf16, transposed to [proj][n=64][k=1024] ----
// proj 0 (Q) folds the 1/sqrt(64) scale.
__global__ __launch_bounds__(256) void wt_kernel(const float* __restrict__ Wq,
                                                 const float* __restrict__ Wk,
                                                 const float* __restrict__ Wv,
                                                 bf16_t* __restrict__ Wt) {
  int gid = blockIdx.x * 256 + threadIdx.x;  // 0 .. 196607
  int proj = gid >> 16;
  int rem = gid & 65535;          // = k*64 + n (row-major read, coalesced)
  int k = rem >> 6, n = rem & 63;
  const float* W = (proj == 0) ? Wq : (proj == 1) ? Wk : Wv;
  float v = W[rem];
  if (proj == 0) v *= 0.125f;
  Wt[proj * 65536 + n * 1024 + k] = (bf16_t)v;
}

// ---------------- kernel 1: QKV projection ------------------------------------------
// grid 256 (1 block/CU), block 512 (8 waves). Block owns 6 consecutive 16-row tiles
// of the flat [3*8192] row space. Wave w holds W[64n][k-slice 128w..] in 64 VGPRs,
// loaded ONCE per block (W traffic 33 MB total). X staged to a shared 64KB LDS tile
// with 1KB-contiguous global_load_lds instructions (inverse-swizzled source, rule
// #21), double-buffered; per-wave k-slice MFMA; 8-way k-merge via bf16 LDS.
__global__ __launch_bounds__(512) void proj_kernel(
    const float* __restrict__ Xq, const float* __restrict__ Xk, const float* __restrict__ Xv,
    const bf16_t* __restrict__ Wt,
    bf16_t* __restrict__ Qb, bf16_t* __restrict__ Kb, bf16_t* __restrict__ Vt) {
  __shared__ alignas(16) char Xs[2][65536];      // dbuf X tile [16 rows][4096 B], swz
  __shared__ alignas(16) bf16_t Msm[8][16][64];  // k-merge partials, 16 KB
  __shared__ bf16_t Vsm[16][68];                 // V transpose staging

  int tid = threadIdx.x;
  int w = tid >> 6, lane = tid & 63;
  int l15 = lane & 15, g = lane >> 4;
  int bid = blockIdx.x;

  bf16x8 Wf[4][4];   // [ct][j]: W[n=ct*16+l15][k = w*128 + j*32 + g*8 ..]

  auto loadW = [&](int p) {
    const char* wb = (const char*)Wt + (size_t)p * 131072;
    char* wreg = &Xs[0][0] + w * 16384;   // wave-private 16KB scratch (clobbers Xs!)
#pragma unroll
    for (int i = 0; i < 16; ++i) {
      int n = i * 4 + (lane >> 4);
      const char* src = wb + (size_t)n * 2048 + w * 256 +
                        (((lane & 15) * 16) ^ ((n & 7) << 4));
      gload_lds16(src, wreg + i * 1024);
    }
    asm volatile("s_waitcnt vmcnt(0)" ::: "memory");
    __builtin_amdgcn_sched_barrier(0);
#pragma unroll
    for (int ct = 0; ct < 4; ++ct)
#pragma unroll
      for (int j = 0; j < 4; ++j) {
        int n = ct * 16 + l15;
        Wf[ct][j] = *(const bf16x8*)(wreg + n * 256 + ((j * 64 + g * 16) ^ ((n & 7) << 4)));
      }
  };

  // X staging: 64 x 1KB-contiguous instrs per tile; wave w covers rows 2w, 2w+1.
  auto stageX = [&](int t_glob, int buf) {
    int p = t_glob >> 9, t_in = t_glob & 511;
    const float* X = (p == 0) ? Xq : (p == 1) ? Xk : Xv;
    const char* xb = (const char*)X + (size_t)t_in * 65536;
    char* dst = &Xs[buf][0] + w * 8192;
#pragma unroll
    for (int i = 0; i < 8; ++i) {
      int r = w * 2 + (i >> 2), q = i & 3;
      const char* src = xb + (size_t)r * 4096 + q * 1024 +
                        ((lane * 16) ^ ((r & 7) << 4));
      gload_lds16(src, dst + i * 1024);
    }
  };

  f32x4 acc[4] = {};

  auto computeX = [&](int buf) {
    const char* bp = &Xs[buf][0] + l15 * 4096;
    int swz = (l15 & 7) << 4;
#pragma unroll
    for (int j = 0; j < 4; ++j) {
      int b0 = w * 512 + j * 128 + g * 32;
      float4 u0 = *(const float4*)(bp + (b0 ^ swz));
      float4 u1 = *(const float4*)(bp + ((b0 + 16) ^ swz));
      bf16x8 af;
      af[0] = (bf16_t)u0.x; af[1] = (bf16_t)u0.y; af[2] = (bf16_t)u0.z; af[3] = (bf16_t)u0.w;
      af[4] = (bf16_t)u1.x; af[5] = (bf16_t)u1.y; af[6] = (bf16_t)u1.z; af[7] = (bf16_t)u1.w;
#pragma unroll
      for (int ct = 0; ct < 4; ++ct)
        acc[ct] = mfma16(af, Wf[ct][j], acc[ct]);
    }
  };

  int t0 = bid * 6;
  int cur_p = t0 >> 9;
  loadW(cur_p);
  __syncthreads();            // W frag reads retired before X staging clobbers Xs
  stageX(t0, 0);

#pragma unroll 1
  for (int i = 0; i < 6; ++i) {
    int t = t0 + i;
    int p = t >> 9;
    if (p != cur_p) {         // only 2 blocks in the grid straddle a proj boundary
      __syncthreads();
      loadW(p); cur_p = p;
      __syncthreads();
      stageX(t, i & 1);       // restage (loadW clobbered both X bufs)
    }
    __syncthreads();          // X(t) staged (vmcnt drain); Msm from prev consumed
    if (i < 5) stageX(t + 1, (i + 1) & 1);
    computeX(i & 1);

    // ---- 8-way k-merge ----
#pragma unroll
    for (int ct = 0; ct < 4; ++ct)
#pragma unroll
      for (int r = 0; r < 4; ++r)
        Msm[w][g * 4 + r][ct * 16 + l15] = (bf16_t)acc[ct][r];
#pragma unroll
    for (int ct = 0; ct < 4; ++ct) acc[ct] = (f32x4){0.f, 0.f, 0.f, 0.f};
    lds_barrier();            // LDS-only sync: X(t+1) prefetch stays in flight

    int row = tid >> 5, c0 = (tid & 31) * 2;
    float s0 = 0.f, s1 = 0.f;
#pragma unroll
    for (int w2 = 0; w2 < 8; ++w2) {
      uint32_t u = *(const uint32_t*)&Msm[w2][row][c0];
      s0 += bf2f((uint16_t)u);
      s1 += bf2f((uint16_t)(u >> 16));
    }
    int t_in = t & 511;
    if (p < 2) {
      bf16_t* Ob = (p == 0) ? Qb : Kb;
      bf16_t o2[2] = {(bf16_t)s0, (bf16_t)s1};
      *(uint32_t*)&Ob[(size_t)(t_in * 16 + row) * 64 + c0] = *(const uint32_t*)o2;
    } else {
      bf16_t o2[2] = {(bf16_t)s0, (bf16_t)s1};
      *(uint32_t*)&Vsm[row][c0] = *(const uint32_t*)o2;
      lds_barrier();
      if (tid < 128) {
        int d = tid >> 1, h = tid & 1;
        int b = t_in >> 7;
        int s_ = (t_in & 127) * 16 + h * 8;
        bf16_t tmp[8];
#pragma unroll
        for (int s2 = 0; s2 < 8; ++s2) tmp[s2] = Vsm[h * 8 + s2][d];
        *(uint4*)(Vt + ((size_t)(b * 64 + d)) * 2048 + s_) = *(const uint4*)tmp;
      }
    }
  }
}

// ---------------- kernel 2: causal flash attention, QBLK=32, KV-split 8 waves ------
// grid (64, 4), block 512 (8 waves), ~1 block/CU. Block owns 32 q-rows (2 row-groups
// per wave); wave w handles KV tiles w, w+8, ... with private flash state; merged at
// the end via LDS. K/V frags straight from L2/L3; no barriers in the main loop.
#define NW 8
__global__ __launch_bounds__(512) void attn_kernel(
    const bf16_t* __restrict__ Qb, const bf16_t* __restrict__ Kb,
    const bf16_t* __restrict__ Vt, float* __restrict__ Out) {
  __shared__ alignas(16) char Psm[NW * 4096];   // per-wave 32x64 P tiles (swizzled)
  __shared__ float accL[NW][32][64];            // 64 KB
  __shared__ float mL[NW][32];
  __shared__ float lL[NW][32];

  int b = blockIdx.y;
  int x = blockIdx.x;
  int qt = (b >= 2) ? (63 - x) : x;    // pair heavy+light across CUs
  int q0 = qt * 32;
  int tid = threadIdx.x;
  int w = tid >> 6, lane = tid & 63;
  int l15 = lane & 15, g = lane >> 4;
  char* Pw = Psm + w * 4096;

  bf16x8 qf[2][2];
#pragma unroll
  for (int h = 0; h < 2; ++h) {
    size_t qrow = (size_t)(b * 2048 + q0 + h * 16 + l15) * 64;
    qf[h][0] = *(const bf16x8*)(Qb + qrow + g * 8);
    qf[h][1] = *(const bf16x8*)(Qb + qrow + 32 + g * 8);
  }

  float m_run[2][4], l_run[2][4];
  f32x4 acc_o[2][4] = {};
#pragma unroll
  for (int h = 0; h < 2; ++h)
#pragma unroll
    for (int r = 0; r < 4; ++r) { m_run[h][r] = -1e30f; l_run[h][r] = 0.f; }

  int ntiles = (q0 + 95) >> 6;         // ceil((q0+32)/64)
  const bf16_t* kbase = Kb + (size_t)b * 2048 * 64;
  const bf16_t* vbase = Vt + (size_t)b * 64 * 2048;

  for (int t = w; t < ntiles; t += NW) {
    int kv0 = t * 64;
    // S = Q K^T  (K frags shared across the two row-groups)
    f32x4 s[2][4] = {};
#pragma unroll
    for (int ct = 0; ct < 4; ++ct) {
      const bf16_t* kr = kbase + (size_t)(kv0 + ct * 16 + l15) * 64 + g * 8;
      bf16x8 kf0 = *(const bf16x8*)kr;
      bf16x8 kf1 = *(const bf16x8*)(kr + 32);
#pragma unroll
      for (int h = 0; h < 2; ++h) {
        s[h][ct] = mfma16(qf[h][0], kf0, s[h][ct]);
        s[h][ct] = mfma16(qf[h][1], kf1, s[h][ct]);
      }
    }
    if (t == ntiles - 1) {  // diagonal tile: causal mask
#pragma unroll
      for (int h = 0; h < 2; ++h)
#pragma unroll
        for (int ct = 0; ct < 4; ++ct)
#pragma unroll
          for (int r = 0; r < 4; ++r) {
            int kg_ = kv0 + ct * 16 + l15;
            int qg_ = q0 + h * 16 + g * 4 + r;
            if (kg_ > qg_) s[h][ct][r] = -1e30f;
          }
    }

    // online softmax (row = h*16 + g*4 + r)
#pragma unroll
    for (int h = 0; h < 2; ++h)
#pragma unroll
      for (int r = 0; r < 4; ++r) {
        float mx = fmaxf(fmaxf(s[h][0][r], s[h][1][r]), fmaxf(s[h][2][r], s[h][3][r]));
        mx = fmaxf(mx, __shfl_xor(mx, 1, 64));
        mx = fmaxf(mx, __shfl_xor(mx, 2, 64));
        mx = fmaxf(mx, __shfl_xor(mx, 4, 64));
        mx = fmaxf(mx, __shfl_xor(mx, 8, 64));
        float mnew = fmaxf(m_run[h][r], mx);
        float scale = exp2f((m_run[h][r] - mnew) * L2E);
        m_run[h][r] = mnew;
        float ps = 0.f;
        int qrl = h * 16 + g * 4 + r;
        char* pb = Pw + qrl * 128;
        int swp = (qrl & 7) << 4;
#pragma unroll
        for (int ct = 0; ct < 4; ++ct) {
          float p = exp2f((s[h][ct][r] - mnew) * L2E);
          ps += p;
          *(bf16_t*)(pb + ((ct * 32 + l15 * 2) ^ swp)) = (bf16_t)p;
        }
        ps += __shfl_xor(ps, 1, 64);
        ps += __shfl_xor(ps, 2, 64);
        ps += __shfl_xor(ps, 4, 64);
        ps += __shfl_xor(ps, 8, 64);
        l_run[h][r] = l_run[h][r] * scale + ps;
#pragma unroll
        for (int dt = 0; dt < 4; ++dt) acc_o[h][dt][r] *= scale;
      }

    // O += P V   (V frags shared across the two row-groups)
    int swpr = (l15 & 7) << 4;
#pragma unroll
    for (int ks = 0; ks < 2; ++ks) {
      bf16x8 pf0 = *(const bf16x8*)(Pw + l15 * 128 + ((ks * 64 + g * 16) ^ swpr));
      bf16x8 pf1 = *(const bf16x8*)(Pw + (16 + l15) * 128 + ((ks * 64 + g * 16) ^ swpr));
#pragma unroll
      for (int dt = 0; dt < 4; ++dt) {
        const bf16_t* vr = vbase + (size_t)(dt * 16 + l15) * 2048 + kv0 + ks * 32 + g * 8;
        bf16x8 vf = *(const bf16x8*)vr;
        acc_o[0][dt] = mfma16(pf0, vf, acc_o[0][dt]);
        acc_o[1][dt] = mfma16(pf1, vf, acc_o[1][dt]);
      }
    }
  }

  // publish per-wave partial state
  if (l15 == 0) {
#pragma unroll
    for (int h = 0; h < 2; ++h)
#pragma unroll
      for (int r = 0; r < 4; ++r) {
        mL[w][h * 16 + g * 4 + r] = m_run[h][r];
        lL[w][h * 16 + g * 4 + r] = l_run[h][r];
      }
  }
#pragma unroll
  for (int h = 0; h < 2; ++h)
#pragma unroll
    for (int dt = 0; dt < 4; ++dt)
#pragma unroll
      for (int r = 0; r < 4; ++r)
        accL[w][h * 16 + g * 4 + r][dt * 16 + l15] = acc_o[h][dt][r];
  __syncthreads();

  // merge 8 partials: thread -> (row = tid>>4, 4 d's = (tid&15)*4)
  int row = tid >> 4, c0 = (tid & 15) * 4;
  float M = -1e30f;
#pragma unroll
  for (int w2 = 0; w2 < NW; ++w2) M = fmaxf(M, mL[w2][row]);
  float L = 0.f;
  f32x4 o = {0.f, 0.f, 0.f, 0.f};
#pragma unroll
  for (int w2 = 0; w2 < NW; ++w2) {
    float sc = exp2f((mL[w2][row] - M) * L2E);
    L += lL[w2][row] * sc;
    f32x4 a = *(const f32x4*)&accL[w2][row][c0];
    o[0] += sc * a[0]; o[1] += sc * a[1]; o[2] += sc * a[2]; o[3] += sc * a[3];
  }
  float inv = 1.0f / L;
  float4 o4 = {o[0] * inv, o[1] * inv, o[2] * inv, o[3] * inv};
  *(float4*)&Out[(size_t)(b * 2048 + q0 + row) * 64 + c0] = o4;
}

extern "C" void kernel_launch(void* const* d_in, const int* in_sizes, int n_in,
                              void* d_out, int out_size, void* d_ws, size_t ws_size,
                              hipStream_t stream) {
  const float* Xk = (const float*)d_in[0];
  const float* Xv = (const float*)d_in[1];
  const float* Xq = (const float*)d_in[2];
  const float* Wq = (const float*)d_in[3];
  const float* Wk = (const float*)d_in[4];
  const float* Wv = (const float*)d_in[5];
  float* Out = (float*)d_out;

  bf16_t* ws = (bf16_t*)d_ws;
  bf16_t* Qb = ws;                 // [8192][64]   bf16, pre-scaled by 0.125
  bf16_t* Kb = ws + 524288;        // [8192][64]   bf16
  bf16_t* Vt = ws + 1048576;       // [4][64][2048] bf16 (V transposed)
  bf16_t* Wt = ws + 1572864;       // [3][64][1024] bf16 (weights transposed)

  wt_kernel<<<dim3(768), dim3(256), 0, stream>>>(Wq, Wk, Wv, Wt);
  proj_kernel<<<dim3(256), dim3(512), 0, stream>>>(Xq, Xk, Xv, Wt, Qb, Kb, Vt);
  attn_kernel<<<dim3(64, 4), dim3(512), 0, stream>>>(Qb, Kb, Vt, Out);
}